// Round 6
// baseline (89.091 us; speedup 1.0000x reference)
//
#include <hip/hip_runtime.h>

#define BLOCK 8
#define NGRID 512

// ---------------------------------------------------------------------------
// Compile-time replication of
//   np.random.RandomState(0).choice(np.array([1.0,3.0],f32), size=(512,8))
// (MT19937 legacy scalar seeding, one 32-bit draw per value, value = draw&1).
// Bit i of pattern byte = element i: g[i] = bit ? 3.0f : 1.0f.
// Dedup (first occurrence) is argmax-neutral. kenc = 255 - dedup_index, so
// "ties -> max kenc" == numpy first-max. Scan order = bit-reversed ascending
// (maximizes shared low-bit spine prefixes); selection is order-independent.
// SCORE PIPELINE IS BIT-FROZEN (R0/R2/R4, absmax 0.0078125): chain-order fma
// spine, lone f32 square, exact-pow2 or Markstein CR division, exact ties.
// ---------------------------------------------------------------------------
struct Sched {
  int nd;                      // distinct patterns (~222)
  unsigned char kpat[256];     // kenc -> pattern byte (epilogue gather)
  unsigned char dfs_pat[256];  // scan ordinal -> pattern byte
  unsigned char dfs_ken[256];  // scan ordinal -> kenc
  unsigned char lowbit[256];   // ordinal -> lowest differing bit vs prev (0 for j=0)
  unsigned char csn[32];       // chunk -> member count (chunks of 8)
  unsigned char cslot[32][8];  // chunk, i -> slot (ordinal & 7), kenc-ascending
  unsigned char cken[32][8];   // chunk, i -> kenc,                kenc-ascending
};

constexpr unsigned char bitrev8c(unsigned v) {
  unsigned r = 0;
  for (int i = 0; i < 8; ++i) r |= ((v >> i) & 1u) << (7 - i);
  return (unsigned char)r;
}
constexpr int popcount8c(int v) {
  int p = 0;
  for (int i = 0; i < 8; ++i) p += (v >> i) & 1;
  return p;
}
constexpr int ctz8c(int v) {
  for (int i = 0; i < 8; ++i) if ((v >> i) & 1) return i;
  return 0;
}

constexpr Sched make_sched() {
  Sched t{};
  bool exists[256] = {};
  unsigned char kenc[256] = {};
  unsigned mt[624] = {};
  {
    unsigned s = 0u;
    for (int i = 0; i < 624; ++i) {
      mt[i] = s;
      s = 1812433253u * (s ^ (s >> 30)) + (unsigned)(i + 1);
    }
  }
  int pos = 624;
  int nd = 0;
  for (int j = 0; j < NGRID; ++j) {
    unsigned char b = 0;
    for (int i = 0; i < BLOCK; ++i) {
      if (pos == 624) {
        for (int k = 0; k < 624; ++k) {
          int k1 = (k + 1 < 624) ? k + 1 : 0;
          int k397 = (k + 397 < 624) ? k + 397 : k + 397 - 624;
          unsigned y = (mt[k] & 0x80000000u) | (mt[k1] & 0x7fffffffu);
          unsigned v = mt[k397] ^ (y >> 1);
          if (y & 1u) v ^= 0x9908b0dfu;
          mt[k] = v;
        }
        pos = 0;
      }
      unsigned y = mt[pos++];
      y ^= y >> 11;
      y ^= (y << 7) & 0x9d2c5680u;
      y ^= (y << 15) & 0xefc60000u;
      y ^= y >> 18;
      if (y & 1u) b |= (unsigned char)(1u << i);
    }
    if (!exists[b]) {
      exists[b] = true;
      kenc[b] = (unsigned char)(255 - nd);
      t.kpat[255 - nd] = b;
      ++nd;
    }
  }
  t.nd = nd;
  int m = 0;
  for (int r = 0; r < 256; ++r) {
    unsigned char b = bitrev8c((unsigned)r);
    if (exists[b]) {
      t.dfs_pat[m] = b;
      t.dfs_ken[m] = kenc[b];
      ++m;
    }
  }
  t.lowbit[0] = 0;
  for (int j = 1; j < nd; ++j)
    t.lowbit[j] = (unsigned char)ctz8c(t.dfs_pat[j] ^ t.dfs_pat[j - 1]);
  int nc = (nd + 7) / 8;
  for (int c = 0; c < nc; ++c) {
    int n = nd - 8 * c; if (n > 8) n = 8;
    t.csn[c] = (unsigned char)n;
    unsigned char sl[8] = {}, ke[8] = {};
    for (int i = 0; i < n; ++i) { sl[i] = (unsigned char)i; ke[i] = t.dfs_ken[8 * c + i]; }
    for (int i = 1; i < n; ++i) {
      unsigned char ks = ke[i], ss = sl[i];
      int p = i - 1;
      while (p >= 0 && ke[p] > ks) { ke[p + 1] = ke[p]; sl[p + 1] = sl[p]; --p; }
      ke[p + 1] = ks; sl[p + 1] = ss;
    }
    for (int i = 0; i < n; ++i) { t.cslot[c][i] = sl[i]; t.cken[c][i] = ke[i]; }
  }
  return t;
}

constexpr Sched SC = make_sched();
constexpr int ND = SC.nd;
static_assert(ND > 0 && ND <= 256, "sanity");

constexpr unsigned long long pack_klut(int c) {
  unsigned long long v = 0ull;
  for (int i = 0; i < 8; ++i)
    v |= (unsigned long long)SC.cken[c][i] << (8 * i);
  return v;
}

__device__ __constant__ const unsigned char g_pat[256] = {
#define P1(z) SC.kpat[z]
#define P8(z) P1(z), P1(z+1), P1(z+2), P1(z+3), P1(z+4), P1(z+5), P1(z+6), P1(z+7)
#define P64(z) P8(z), P8(z+8), P8(z+16), P8(z+24), P8(z+32), P8(z+40), P8(z+48), P8(z+56)
    P64(0), P64(64), P64(128), P64(192)
#undef P64
#undef P8
#undef P1
};

static __device__ __forceinline__ float max3f(float a, float b, float c) {
  return __builtin_fmaxf(__builtin_fmaxf(a, b), c);   // folds to v_max3_f32
}

// Dual-stream trie scan step: two independent blocks (A,B) interleaved for ILP.
template <int J>
struct Step {
  static __device__ __forceinline__ void run(
      const float (&aA)[8], const float (&aB)[8],
      float (&spA)[9], float (&spB)[9],
      float (&sA)[8], float (&sB)[8],
      float &gbA, int &gkA, float &gbB, int &gkB) {
    constexpr int pat = SC.dfs_pat[J];
    constexpr int p0 = (J == 0) ? 0 : SC.lowbit[J];
#pragma unroll
    for (int l = 0; l < 8; ++l) {
      if (l >= p0) {
        if ((pat >> l) & 1) {
          spA[l + 1] = __builtin_fmaf(aA[l], 3.0f, spA[l]);
          spB[l + 1] = __builtin_fmaf(aB[l], 3.0f, spB[l]);
        } else {
          spA[l + 1] = spA[l] + aA[l];
          spB[l + 1] = spB[l] + aB[l];
        }
      }
    }
    float ddA = spA[8] * spA[8];
    float ddB = spB[8] * spB[8];
    constexpr int pc = popcount8c(pat);
    float scA, scB;
    if constexpr (pc == 0)      { scA = ddA * 0.125f;    scB = ddB * 0.125f; }
    else if constexpr (pc == 1) { scA = ddA * 0.0625f;   scB = ddB * 0.0625f; }
    else if constexpr (pc == 3) { scA = ddA * 0.03125f;  scB = ddB * 0.03125f; }
    else if constexpr (pc == 7) { scA = ddA * 0.015625f; scB = ddB * 0.015625f; }
    else {
      constexpr float nf = (float)(8 * (1 + pc));
      constexpr float rcf = 1.0f / nf;
      float qA = ddA * rcf, qB = ddB * rcf;
      float rA = __builtin_fmaf(-nf, qA, ddA);
      float rB = __builtin_fmaf(-nf, qB, ddB);
      scA = __builtin_fmaf(rA, rcf, qA);   // Markstein: == fl32(dd/nf)
      scB = __builtin_fmaf(rB, rcf, qB);
    }
    sA[J & 7] = scA;
    sB[J & 7] = scB;

    if constexpr (((J & 7) == 7) || (J == ND - 1)) {
      constexpr int c = J >> 3;
      constexpr int n = SC.csn[c];
      float cmA, cmB;
      if constexpr (n == 8) {
        cmA = max3f(max3f(sA[0], sA[1], sA[2]), max3f(sA[3], sA[4], sA[5]),
                    __builtin_fmaxf(sA[6], sA[7]));
        cmB = max3f(max3f(sB[0], sB[1], sB[2]), max3f(sB[3], sB[4], sB[5]),
                    __builtin_fmaxf(sB[6], sB[7]));
      } else {
        cmA = sA[0]; cmB = sB[0];
#pragma unroll
        for (int i = 1; i < n; ++i) {
          cmA = __builtin_fmaxf(cmA, sA[i]);
          cmB = __builtin_fmaxf(cmB, sB[i]);
        }
      }
      int ckA = 0, ckB = 0;
#pragma unroll
      for (int i = 0; i < n; ++i) {  // kenc ascending: last write = min original k
        ckA = (sA[SC.cslot[c][i]] == cmA) ? i : ckA;
        ckB = (sB[SC.cslot[c][i]] == cmB) ? i : ckB;
      }
      constexpr unsigned long long klut = pack_klut(c);
      int keA = (int)((unsigned)(klut >> (ckA << 3)) & 0xFFu);
      int keB = (int)((unsigned)(klut >> (ckB << 3)) & 0xFFu);
      bool rA = (cmA > gbA) || ((cmA == gbA) && (keA > gkA));
      bool rB = (cmB > gbB) || ((cmB == gbB) && (keB > gkB));
      gbA = rA ? cmA : gbA;  gkA = rA ? keA : gkA;
      gbB = rB ? cmB : gbB;  gkB = rB ? keB : gkB;
    }
    if constexpr (J + 1 < ND)
      Step<J + 1>::run(aA, aB, spA, spB, sA, sB, gbA, gkA, gbB, gkB);
  }
};

__global__ __launch_bounds__(256, 4) void _IQ2XSQuantWeight_12945031430379_kernel(
    const float* __restrict__ w, float* __restrict__ out, int nb) {
  int t = blockIdx.x * blockDim.x + threadIdx.x;
  int half = (nb + 1) >> 1;
  if (t >= half) return;
  bool hasB = (t + half) < nb;

  const float4* wpA = reinterpret_cast<const float4*>(w) + (size_t)2 * t;
  const float4* wpB = reinterpret_cast<const float4*>(w) + (size_t)2 * (hasB ? (t + half) : t);
  float4 A0 = wpA[0], A1 = wpA[1];
  float4 B0 = wpB[0], B1 = wpB[1];
  float wvA[BLOCK] = {A0.x, A0.y, A0.z, A0.w, A1.x, A1.y, A1.z, A1.w};
  float wvB[BLOCK] = {B0.x, B0.y, B0.z, B0.w, B1.x, B1.y, B1.z, B1.w};

  float aA[BLOCK], aB[BLOCK];
  unsigned sbA = 0u, sbB = 0u;   // per-element sign bits of w
#pragma unroll
  for (int i = 0; i < BLOCK; ++i) {
    aA[i] = __builtin_fabsf(wvA[i]);
    aB[i] = __builtin_fabsf(wvB[i]);
    sbA |= (__float_as_uint(wvA[i]) >> 31) << i;
    sbB |= (__float_as_uint(wvB[i]) >> 31) << i;
  }
  // wvA/wvB dead from here: epilogue uses a[], sign bits, zero-guard on a==0.

  float spA[9], spB[9];
  spA[0] = 0.0f; spB[0] = 0.0f;
  float sA[8], sB[8];
  float gbA = -1.0f, gbB = -1.0f;
  int gkA = 0, gkB = 0;
  Step<0>::run(aA, aB, spA, spB, sA, sB, gbA, gkA, gbB, gkB);

#pragma unroll
  for (int blk = 0; blk < 2; ++blk) {
    if (blk == 1 && !hasB) break;
    const float* a = blk ? aB : aA;
    unsigned sb = blk ? sbB : sbA;
    int gk = blk ? gkB : gkA;
    unsigned bits = (unsigned)g_pat[gk];        // divergent 1-byte gather, L1

    // numerator: p_i = fl(a*q), q in {1,3}; numpy pairwise tree sum
    float p[BLOCK];
#pragma unroll
    for (int i = 0; i < BLOCK; ++i) {
      float a3 = a[i] * 3.0f;
      p[i] = ((bits >> i) & 1u) ? a3 : a[i];
    }
    float num = ((p[0] + p[1]) + (p[2] + p[3])) + ((p[4] + p[5]) + (p[6] + p[7]));

    int popc = __popc(bits);
    float normf = (float)(8 + (popc << 3));
    float scale = num / normf;                  // IEEE CR f32 divide (once)
    float s3 = scale * 3.0f;

    float o[BLOCK];
#pragma unroll
    for (int i = 0; i < BLOCK; ++i) {
      float mag = ((bits >> i) & 1u) ? s3 : scale;
      // copysign(mag, w) via sign-bit OR; exact-zero w -> 0 (a[i]==0)
      unsigned ob = __float_as_uint(mag) | (((sb >> i) & 1u) << 31);
      float v = __uint_as_float(ob);
      o[i] = (a[i] == 0.0f) ? 0.0f : v;         // o = deq (== w + (deq-w) up to 1 ulp(w))
    }

    float4 o0 = {o[0], o[1], o[2], o[3]};
    float4 o1 = {o[4], o[5], o[6], o[7]};
    float4* op = reinterpret_cast<float4*>(out) + (size_t)2 * (blk ? (t + half) : t);
    op[0] = o0;
    op[1] = o1;
  }
}

extern "C" void kernel_launch(void* const* d_in, const int* in_sizes, int n_in,
                              void* d_out, int out_size, void* d_ws, size_t ws_size,
                              hipStream_t stream) {
  (void)n_in; (void)d_ws; (void)ws_size; (void)out_size;
  const float* w = (const float*)d_in[0];
  float* out = (float*)d_out;
  int n = in_sizes[0];
  int nb = n / BLOCK;
  int half = (nb + 1) >> 1;
  int threads = 256;
  int blocks = (half + threads - 1) / threads;
  _IQ2XSQuantWeight_12945031430379_kernel<<<blocks, threads, 0, stream>>>(w, out, nb);
}